// Round 15
// baseline (73.512 us; speedup 1.0000x reference)
//
#include <hip/hip_runtime.h>
#include <hip/hip_bf16.h>
#include <hip/hip_fp16.h>

#define DIM 512
#define NUM_HEADS 16
#define HEAD_DIM 32
#define WHALF 128
#define MEMN 16
#define SEQ 2048
#define BATCH 2
#define T_TOT (SEQ + MEMN)                 // 2064
#define MROWS (BATCH * T_TOT)              // 4128
#define OROWS (BATCH * SEQ)                // 4096
#define QT 128                             // queries per attn block (8 waves)
#define MAXU 416                           // pad32 of max union window (401)
#define KSTR 40                            // sK row stride (halves), 80B
#define VPLANE (MAXU * 16 * 2)             // bytes per sV plane = 13312

typedef _Float16 f16x8 __attribute__((ext_vector_type(8)));
typedef __fp16   f16raw2 __attribute__((ext_vector_type(2)));   // cvt_pkrtz return
typedef float    f32x4 __attribute__((ext_vector_type(4)));
typedef uint     u32x2 __attribute__((ext_vector_type(2)));

#define QSCALE 0.17677669529663687f        // 1/sqrt(32), folded into Wq/bq

// gfx950 LDS transpose read: lane l, elem j <- lds[(l&15) + j*16 + (l>>4)*64]
__device__ __forceinline__ u32x2 tr64(uint addr) {
    u32x2 r;
    asm volatile("ds_read_b64_tr_b16 %0, %1" : "=v"(r) : "v"(addr));
    return r;
}

// ---------------------------------------------------------------------------
// Prep: W[k][n] -> Wfrag in exact MFMA B-fragment order:
//   Wfrag[((nt*16 + ks)*64 + lane)*8 + j] = W[ks*32 + (lane>>4)*8 + j][nt*16 + (lane&15)] * ws
// so a wave's b-frag load is base + lane*16B (coalesced 1KB), straight from L2.
// ---------------------------------------------------------------------------
__global__ __launch_bounds__(256) void prep_wfrag(
    const float* __restrict__ Wq, const float* __restrict__ Wk,
    const float* __restrict__ Wv, const float* __restrict__ Wo,
    ushort* __restrict__ Fq, ushort* __restrict__ Fk,
    ushort* __restrict__ Fv, ushort* __restrict__ Fo)
{
    const int w = blockIdx.z;
    const float* W = w == 0 ? Wq : (w == 1 ? Wk : (w == 2 ? Wv : Wo));
    ushort*     F  = w == 0 ? Fq : (w == 1 ? Fk : (w == 2 ? Fv : Fo));
    const float ws = (w == 0) ? QSCALE : 1.0f;

    __shared__ float sT[64][65];
    const int n0 = (blockIdx.x & 7) * 64;
    const int k0 = (blockIdx.x >> 3) * 64;

    for (int e = threadIdx.x; e < 1024; e += 256) {
        const int r  = e >> 4;
        const int c4 = e & 15;
        const float4 f = *(const float4*)(W + (size_t)(k0 + r) * DIM + n0 + c4 * 4);
        sT[r][c4 * 4 + 0] = f.x;
        sT[r][c4 * 4 + 1] = f.y;
        sT[r][c4 * 4 + 2] = f.z;
        sT[r][c4 * 4 + 3] = f.w;
    }
    __syncthreads();
    for (int e = threadIdx.x; e < 512; e += 256) {
        const int nn   = e >> 7;        // 0..3
        const int kss  = (e >> 6) & 1;  // 0..1
        const int lane = e & 63;
        const int fr = lane & 15, fq = lane >> 4;
        union { _Float16 hh[8]; uint4 u4; } o;
        #pragma unroll
        for (int j = 0; j < 8; ++j)
            o.hh[j] = (_Float16)(sT[kss * 32 + fq * 8 + j][nn * 16 + fr] * ws);
        const size_t idx =
            ((size_t)((n0 / 16 + nn) * 16 + (k0 / 32 + kss)) * 64 + lane) * 8;
        *(uint4*)(F + idx) = o.u4;
    }
}

// ---------------------------------------------------------------------------
// Fused QKV GEMM: 32-row x full-512-col tiles; A = fp32 inputs (mem-mapped)
// converted to fp16 during LDS staging (each A row read from HBM exactly once);
// B fragments read directly from L2-resident Wfrag (no LDS, no barrier).
// 4 waves; wave wn owns cols [wn*128, wn*128+128) = 8 n-frags.
// ---------------------------------------------------------------------------
__global__ __launch_bounds__(256) void gemm_qkv_f(
    const float* __restrict__ q, const float* __restrict__ k,
    const float* __restrict__ v, const float* __restrict__ memp,
    const ushort* __restrict__ Fq, const ushort* __restrict__ Fk,
    const ushort* __restrict__ Fv,
    const float* __restrict__ bq, const float* __restrict__ bk,
    const float* __restrict__ bv,
    ushort* __restrict__ Qc, ushort* __restrict__ Kc, ushort* __restrict__ Vc)
{
    const int w = blockIdx.z;
    const float*  X  = w == 0 ? q  : (w == 1 ? k  : v);
    const ushort* F  = w == 0 ? Fq : (w == 1 ? Fk : Fv);
    const float*  bi = w == 0 ? bq : (w == 1 ? bk : bv);
    ushort*       Co = w == 0 ? Qc : (w == 1 ? Kc : Vc);
    const float bscale = (w == 0) ? QSCALE : 1.0f;

    __shared__ _Float16 sA[32][72];

    const int tid  = threadIdx.x;
    const int row0 = blockIdx.x * 32;
    const int wave = tid >> 6, lane = tid & 63;
    const int fr = lane & 15, fq = lane >> 4;
    const int ncol0 = wave * 128;

    f32x4 acc[2][8];
    #pragma unroll
    for (int n = 0; n < 8; ++n) {
        const float bb = bi[ncol0 + n * 16 + fr] * bscale;
        acc[0][n] = (f32x4){bb, bb, bb, bb};
        acc[1][n] = (f32x4){bb, bb, bb, bb};
    }

    // A staging source for this thread (fixed row, varying k)
    const int r  = tid >> 3, cc = tid & 7;
    const int gr = row0 + r;                       // MROWS = 129*32 exact
    const int bb_ = gr >= T_TOT ? 1 : 0;
    const int t   = gr - bb_ * T_TOT;
    const float* srcrow = (t < MEMN)
        ? (memp + (size_t)t * DIM)
        : (X + ((size_t)bb_ * SEQ + (t - MEMN)) * DIM);

    for (int step = 0; step < 8; ++step) {
        const int k0 = step * 64;
        __syncthreads();
        {
            const float* src = srcrow + k0 + cc * 8;
            const float4 a0 = ((const float4*)src)[0];
            const float4 a1 = ((const float4*)src)[1];
            union { _Float16 hh[8]; uint4 u4; } o;
            o.hh[0] = (_Float16)a0.x; o.hh[1] = (_Float16)a0.y;
            o.hh[2] = (_Float16)a0.z; o.hh[3] = (_Float16)a0.w;
            o.hh[4] = (_Float16)a1.x; o.hh[5] = (_Float16)a1.y;
            o.hh[6] = (_Float16)a1.z; o.hh[7] = (_Float16)a1.w;
            *(uint4*)&sA[r][cc * 8] = o.u4;
        }
        __syncthreads();
        #pragma unroll
        for (int kk = 0; kk < 2; ++kk) {
            const int ks = step * 2 + kk;
            f16x8 a[2], b[8];
            #pragma unroll
            for (int m = 0; m < 2; ++m)
                a[m] = *(const f16x8*)&sA[m * 16 + fr][kk * 32 + fq * 8];
            #pragma unroll
            for (int n = 0; n < 8; ++n)
                b[n] = *(const f16x8*)(F +
                    ((size_t)((wave * 8 + n) * 16 + ks) * 64 + lane) * 8);
            #pragma unroll
            for (int m = 0; m < 2; ++m)
                #pragma unroll
                for (int n = 0; n < 8; ++n)
                    acc[m][n] = __builtin_amdgcn_mfma_f32_16x16x32_f16(
                        a[m], b[n], acc[m][n], 0, 0, 0);
        }
    }

    #pragma unroll
    for (int m = 0; m < 2; ++m)
        #pragma unroll
        for (int n = 0; n < 8; ++n)
            #pragma unroll
            for (int j = 0; j < 4; ++j) {
                const int row = row0 + m * 16 + fq * 4 + j;
                const int col = ncol0 + n * 16 + fr;
                _Float16 h = (_Float16)acc[m][n][j];
                Co[(size_t)row * 512 + col] = *(ushort*)&h;
            }
}

// ---------------------------------------------------------------------------
// Out projection: 16-row x 512-col tiles, 256 blocks (= 1/CU), C read once.
// ---------------------------------------------------------------------------
__global__ __launch_bounds__(256) void gemm_out_f(
    const ushort* __restrict__ A, const ushort* __restrict__ F,
    const float* __restrict__ bias, float* __restrict__ C)
{
    __shared__ _Float16 sA[16][72];

    const int tid  = threadIdx.x;
    const int row0 = blockIdx.x * 16;
    const int wave = tid >> 6, lane = tid & 63;
    const int fr = lane & 15, fq = lane >> 4;
    const int ncol0 = wave * 128;

    f32x4 acc[8];
    #pragma unroll
    for (int n = 0; n < 8; ++n) {
        const float bb = bias[ncol0 + n * 16 + fr];
        acc[n] = (f32x4){bb, bb, bb, bb};
    }

    for (int step = 0; step < 8; ++step) {
        const int k0 = step * 64;
        __syncthreads();
        if (tid < 128) {
            const int r = tid >> 3, cc = tid & 7;
            *(uint4*)&sA[r][cc * 8] =
                *(const uint4*)(A + (size_t)(row0 + r) * 512 + k0 + cc * 8);
        }
        __syncthreads();
        #pragma unroll
        for (int kk = 0; kk < 2; ++kk) {
            const int ks = step * 2 + kk;
            const f16x8 a = *(const f16x8*)&sA[fr][kk * 32 + fq * 8];
            f16x8 b[8];
            #pragma unroll
            for (int n = 0; n < 8; ++n)
                b[n] = *(const f16x8*)(F +
                    ((size_t)((wave * 8 + n) * 16 + ks) * 64 + lane) * 8);
            #pragma unroll
            for (int n = 0; n < 8; ++n)
                acc[n] = __builtin_amdgcn_mfma_f32_16x16x32_f16(
                    a, b[n], acc[n], 0, 0, 0);
        }
    }

    #pragma unroll
    for (int n = 0; n < 8; ++n)
        #pragma unroll
        for (int j = 0; j < 4; ++j) {
            const int row = row0 + fq * 4 + j;
            const int col = ncol0 + n * 16 + fr;
            C[(size_t)row * 512 + col] = acc[n][j];
        }
}

// ---------------------------------------------------------------------------
// MFMA flash attention (unchanged from round 14 — verified).
// ---------------------------------------------------------------------------
__global__ __launch_bounds__(512, 4) void attn_mfma(
    const ushort* __restrict__ Q, const ushort* __restrict__ K,
    const ushort* __restrict__ V, ushort* __restrict__ ctx)
{
    const int tid  = threadIdx.x;
    const int tile = blockIdx.x, h = blockIdx.y, b = blockIdx.z;
    const int wave = tid >> 6, lane = tid & 63;
    const int fr = lane & 15, fq = lane >> 4;
    const int fq8 = fq * 8, fq4 = fq * 4;

    const int i0  = MEMN + tile * QT;
    const int klo = max(MEMN, i0 - WHALF);
    const int khi = min(T_TOT - 1, i0 + QT - 1 + WHALF);
    const int total  = MEMN + khi - klo + 1;           // <= 401
    const int ustage = (total + 31) & ~31;             // pad to 32

    __shared__ ushort sK[MAXU][KSTR];                  // 33.3 KiB
    __shared__ ushort sV[2][MAXU][16];                 // 26.0 KiB (two d-planes)

    const size_t hbase = (size_t)b * T_TOT * DIM + (size_t)h * HEAD_DIM;

    // ---- stage K rows (linear quarters) ----
    for (int idx = tid; idx < ustage * 4; idx += 512) {
        const int u = idx >> 2, c = idx & 3;
        uint4 val = {0, 0, 0, 0};
        if (u < total) {
            const int g = (u < MEMN) ? u : klo + u - MEMN;
            val = *(const uint4*)(K + hbase + (size_t)g * DIM + c * 8);
        }
        *(uint4*)&sK[u][c * 8] = val;
    }
    // ---- stage V into two linear planes: plane p = d in [16p, 16p+16) ----
    for (int idx = tid; idx < ustage * 4; idx += 512) {
        const int pl   = (idx >= ustage * 2) ? 1 : 0;
        const int s    = idx - pl * ustage * 2;
        const int u    = s >> 1, half = s & 1;
        uint4 val = {0, 0, 0, 0};
        if (u < total) {
            const int g = (u < MEMN) ? u : klo + u - MEMN;
            val = *(const uint4*)(V + hbase + (size_t)g * DIM + pl * 16 + half * 8);
        }
        *(uint4*)&sV[pl][u][half * 8] = val;
    }

    // ---- Q fragment (pre-scaled): lane holds Q[q=fr][d=fq*8..+7] ----
    const int iq = i0 + wave * 16 + fr;
    const f16x8 qf = *(const f16x8*)(Q + (size_t)(b * T_TOT + iq) * DIM
                                     + h * HEAD_DIM + fq8);

    const int ulo  = max(iq - WHALF - klo, 0) + MEMN;
    const int uhi  = min(iq + WHALF, khi) - klo + MEMN;
    const int span = uhi - ulo;
    const int iw0  = i0 + wave * 16;
    const int ulo_minw = max(iw0 - WHALF - klo, 0) + MEMN;
    const int ulo_maxw = max(iw0 + 15 - WHALF - klo, 0) + MEMN;
    const int uhi_minw = min(iw0 + WHALF, khi) - klo + MEMN;
    const int uhi_maxw = min(iw0 + 15 + WHALF, khi) - klo + MEMN;
    const int glo = max(1, ulo_minw >> 5);
    const int ghi = uhi_maxw >> 5;

    // per-lane tr-read base (byte addr of sV plane0 + 8*lane)
    const uint vlane = (uint)(size_t)(&sV[0][0][0]) + (uint)(lane * 8);

    __syncthreads();

    const float NEGINF = -__builtin_huge_valf();
    float mns = 0.0f;
    float l   = 0.f;
    f32x4 oc0 = {0, 0, 0, 0}, oc1 = {0, 0, 0, 0};

    // ---------------- group 0: mem rows (unmasked) + rows 16-31 ----------------
    {
        const f16x8 kfA = *(const f16x8*)&sK[fr][fq8];
        const f16x8 kfB = *(const f16x8*)&sK[16 + fr][fq8];
        f32x4 sA = {0, 0, 0, 0}, sB = {0, 0, 0, 0};
        sA = __builtin_amdgcn_mfma_f32_16x16x32_f16(kfA, qf, sA, 0, 0, 0);
        sB = __builtin_amdgcn_mfma_f32_16x16x32_f16(kfB, qf, sB, 0, 0, 0);
        const uint vb = vlane;
        u32x2 t0 = tr64(vb), t1 = tr64(vb + 512);
        u32x2 t2 = tr64(vb + VPLANE), t3 = tr64(vb + VPLANE + 512);
        if (!(16 >= ulo_maxw && 31 <= uhi_minw)) {
            #pragma unroll
            for (int j = 0; j < 4; ++j) {
                const uint uu = (uint)(16 + fq4 + j - ulo);
                sB[j] = (uu <= (uint)span) ? sB[j] : NEGINF;
            }
        }
        float mx = fmaxf(fmaxf(fmaxf(sA[0], sA[1]), fmaxf(sA[2], sA[3])),
                         fmaxf(fmaxf(sB[0], sB[1]), fmaxf(sB[2], sB[3])));
        mx = fmaxf(mx, __shfl_xor(mx, 16));
        mx = fmaxf(mx, __shfl_xor(mx, 32));
        if (!__all(mx <= mns)) {
            const float mn2   = fmaxf(mns, mx);
            const float alpha = __expf(mns - mn2);
            l *= alpha;
            #pragma unroll
            for (int j = 0; j < 4; ++j) { oc0[j] *= alpha; oc1[j] *= alpha; }
            mns = mn2;
        }
        const float p0 = __expf(sA[0] - mns), p1 = __expf(sA[1] - mns);
        const float p2 = __expf(sA[2] - mns), p3 = __expf(sA[3] - mns);
        const float p4 = __expf(sB[0] - mns), p5 = __expf(sB[1] - mns);
        const float p6 = __expf(sB[2] - mns), p7 = __expf(sB[3] - mns);
        l += ((p0 + p1) + (p2 + p3)) + ((p4 + p5) + (p6 + p7));
        union { f16raw2 h2; uint u; } c0, c1, c2, c3;
        c0.h2 = __builtin_amdgcn_cvt_pkrtz(p0, p1);
        c1.h2 = __builtin_amdgcn_cvt_pkrtz(p2, p3);
        c2.h2 = __builtin_amdgcn_cvt_pkrtz(p4, p5);
        c3.h2 = __builtin_amdgcn_cvt_pkrtz(p6, p7);
        union { uint u[4]; f16x8 h; } P;
        P.u[0] = c0.u; P.u[1] = c1.u; P.u[2] = c2.u; P.u[3] = c3.u;
        asm volatile("s_waitcnt lgkmcnt(0)" ::: "memory");
        __builtin_amdgcn_sched_barrier(0);
        union { u32x2 d[2]; f16x8 h; } VA0, VA1;
        VA0.d[0] = t0; VA0.d[1] = t1;
        VA1.d[0] = t2; VA1.d[1] = t3;
        oc0 = __builtin_amdgcn_mfma_f32_16x16x32_f16(VA0.h, P.h, oc0, 0, 0, 0);
        oc1 = __builtin_amdgcn_mfma_f32_16x16x32_f16(VA1.h, P.h, oc1, 0, 0, 0);
    }

    // ---------------- window groups, two per iteration ----------------
    int g = glo;
    for (; g + 1 <= ghi; g += 2) {
        const int ua = g * 32, ub2 = ua + 32;
        const f16x8 kf0 = *(const f16x8*)&sK[ua + fr][fq8];
        const f16x8 kf1 = *(const f16x8*)&sK[ua + 16 + fr][fq8];
        const f16x8 kf2 = *(const f16x8*)&sK[ub2 + fr][fq8];
        const f16x8 kf3 = *(const f16x8*)&sK[ub2 + 16 + fr][fq8];
        f32x4 s0 = {0,0,0,0}, s1 = {0,0,0,0}, s2 = {0,0,0,0}, s3 = {0,0,0,0};
        s0 = __builtin_amdgcn_mfma_f32_16x16x32_f16(kf0, qf, s0, 0, 0, 0);
        s1 = __builtin_amdgcn_mfma_f32_16x16x32_f16(kf1, qf, s1, 0, 0, 0);
        s2 = __builtin_amdgcn_mfma_f32_16x16x32_f16(kf2, qf, s2, 0, 0, 0);
        s3 = __builtin_amdgcn_mfma_f32_16x16x32_f16(kf3, qf, s3, 0, 0, 0);
        const uint vb = vlane + (uint)(ua * 32);
        u32x2 ta0 = tr64(vb),          ta1 = tr64(vb + 512);
        u32x2 ta2 = tr64(vb + VPLANE), ta3 = tr64(vb + VPLANE + 512);
        u32x2 tb0 = tr64(vb + 1024),          tb1 = tr64(vb + 1536);
        u32x2 tb2 = tr64(vb + VPLANE + 1024), tb3 = tr64(vb + VPLANE + 1536);
        #pragma unroll
        for (int cch = 0; cch < 4; ++cch) {
            const int base = ua + cch * 16;
            f32x4& sc = cch == 0 ? s0 : (cch == 1 ? s1 : (cch == 2 ? s2 : s3));
            if (!(base >= ulo_maxw && base + 15 <= uhi_minw)) {
                #pragma unroll
                for (int j = 0; j < 4; ++j) {
                    const uint uu = (uint)(base + fq4 + j - ulo);
                    sc[j] = (uu <= (uint)span) ? sc[j] : NEGINF;
                }
            }
        }
        float mxA = fmaxf(fmaxf(fmaxf(s0[0], s0[1]), fmaxf(s0[2], s0[3])),
                          fmaxf(fmaxf(s1[0], s1[1]), fmaxf(s1[2], s1[3])));
        float mxB = fmaxf(fmaxf(fmaxf(s2[0], s2[1]), fmaxf(s2[2], s2[3])),
                          fmaxf(fmaxf(s3[0], s3[1]), fmaxf(s3[2], s3[3])));
        float mx = fmaxf(mxA, mxB);
        mx = fmaxf(mx, __shfl_xor(mx, 16));
        mx = fmaxf(mx, __shfl_xor(mx, 32));
        if (!__all(mx <= mns)) {
            const float mn2   = fmaxf(mns, mx);
            const float alpha = __expf(mns - mn2);
            l *= alpha;
            #pragma unroll
            for (int j = 0; j < 4; ++j) { oc0[j] *= alpha; oc1[j] *= alpha; }
            mns = mn2;
        }
        const float a0 = __expf(s0[0] - mns), a1 = __expf(s0[1] - mns);
        const float a2 = __expf(s0[2] - mns), a3 = __expf(s0[3] - mns);
        const float a4 = __expf(s1[0] - mns), a5 = __expf(s1[1] - mns);
        const float a6 = __expf(s1[2] - mns), a7 = __expf(s1[3] - mns);
        const float b0 = __expf(s2[0] - mns), b1 = __expf(s2[1] - mns);
        const float b2 = __expf(s2[2] - mns), b3 = __expf(s2[3] - mns);
        const float b4 = __expf(s3[0] - mns), b5 = __expf(s3[1] - mns);
        const float b6 = __expf(s3[2] - mns), b7 = __expf(s3[3] - mns);
        l += (((a0 + a1) + (a2 + a3)) + ((a4 + a5) + (a6 + a7)))
           + (((b0 + b1) + (b2 + b3)) + ((b4 + b5) + (b6 + b7)));
        union { f16raw2 h2; uint u; } d0, d1, d2, d3, e0, e1, e2, e3;
        d0.h2 = __builtin_amdgcn_cvt_pkrtz(a0, a1);
        d1.h2 = __builtin_amdgcn_cvt_pkrtz(a2, a3);
        d2.h2 = __builtin_amdgcn_cvt_pkrtz(a4, a5);
        d3.h2 = __builtin_amdgcn_cvt_pkrtz(a6, a7);
        e0.h2 = __builtin_amdgcn_cvt_pkrtz(b0, b1);
        e1.h2 = __builtin_amdgcn_cvt_pkrtz(b2, b3);
        e2.h2 = __builtin_amdgcn_cvt_pkrtz(b4, b5);
        e3.h2 = __builtin_amdgcn_cvt_pkrtz(b6, b7);
        union { uint u[4]; f16x8 h; } P0, P1;
        P0.u[0] = d0.u; P0.u[1] = d1.u; P0.u[2] = d2.u; P0.u[3] = d3.u;
        P1.u[0] = e0.u; P1.u[1] = e1.u; P1.u[2] = e2.u; P1.u[3] = e3.u;
        asm volatile("s_waitcnt lgkmcnt(0)" ::: "memory");
        __builtin_amdgcn_sched_barrier(0);
        union { u32x2 d[2]; f16x8 h; } A0, A1, B0, B1;
        A0.d[0] = ta0; A0.d[1] = ta1;
        A1.d[0] = ta2; A1.d[1] = ta3;
        B0.d[0] = tb0; B0.d[1] = tb1;
        B1.d[0] = tb2; B1.d[1] = tb3;
        oc0 = __builtin_amdgcn_mfma_f32_16x16x32_f16(A0.h, P0.h, oc0, 0, 0, 0);
        oc1 = __builtin_amdgcn_mfma_f32_16x16x32_f16(A1.h, P0.h, oc1, 0, 0, 0);
        oc0 = __builtin_amdgcn_mfma_f32_16x16x32_f16(B0.h, P1.h, oc0, 0, 0, 0);
        oc1 = __builtin_amdgcn_mfma_f32_16x16x32_f16(B1.h, P1.h, oc1, 0, 0, 0);
    }
    // odd tail group
    if (g <= ghi) {
        const int ua = g * 32;
        const f16x8 kf0 = *(const f16x8*)&sK[ua + fr][fq8];
        const f16x8 kf1 = *(const f16x8*)&sK[ua + 16 + fr][fq8];
        f32x4 s0 = {0,0,0,0}, s1 = {0,0,0,0};
        s0 = __builtin_amdgcn_mfma_f32_16x16x32_f16(kf0, qf, s0, 0, 0, 0);
        s1 = __builtin_amdgcn_mfma_f32_16x16x32_f16(kf1, qf, s1, 0, 0, 0);
        const uint vb = vlane + (uint)(ua * 32);
        u32x2 t0 = tr64(vb),          t1 = tr64(vb + 512);
        u32x2 t2 = tr64(vb + VPLANE), t3 = tr64(vb + VPLANE + 512);
        #pragma unroll
        for (int cch = 0; cch < 2; ++cch) {
            const int base = ua + cch * 16;
            f32x4& sc = cch == 0 ? s0 : s1;
            if (!(base >= ulo_maxw && base + 15 <= uhi_minw)) {
                #pragma unroll
                for (int j = 0; j < 4; ++j) {
                    const uint uu = (uint)(base + fq4 + j - ulo);
                    sc[j] = (uu <= (uint)span) ? sc[j] : NEGINF;
                }
            }
        }
        float mx = fmaxf(fmaxf(fmaxf(s0[0], s0[1]), fmaxf(s0[2], s0[3])),
                         fmaxf(fmaxf(s1[0], s1[1]), fmaxf(s1[2], s1[3])));
        mx = fmaxf(mx, __shfl_xor(mx, 16));
        mx = fmaxf(mx, __shfl_xor(mx, 32));
        if (!__all(mx <= mns)) {
            const float mn2   = fmaxf(mns, mx);
            const float alpha = __expf(mns - mn2);
            l *= alpha;
            #pragma unroll
            for (int j = 0; j < 4; ++j) { oc0[j] *= alpha; oc1[j] *= alpha; }
            mns = mn2;
        }
        const float p0 = __expf(s0[0] - mns), p1 = __expf(s0[1] - mns);
        const float p2 = __expf(s0[2] - mns), p3 = __expf(s0[3] - mns);
        const float p4 = __expf(s1[0] - mns), p5 = __expf(s1[1] - mns);
        const float p6 = __expf(s1[2] - mns), p7 = __expf(s1[3] - mns);
        l += ((p0 + p1) + (p2 + p3)) + ((p4 + p5) + (p6 + p7));
        union { f16raw2 h2; uint u; } c0, c1, c2, c3;
        c0.h2 = __builtin_amdgcn_cvt_pkrtz(p0, p1);
        c1.h2 = __builtin_amdgcn_cvt_pkrtz(p2, p3);
        c2.h2 = __builtin_amdgcn_cvt_pkrtz(p4, p5);
        c3.h2 = __builtin_amdgcn_cvt_pkrtz(p6, p7);
        union { uint u[4]; f16x8 h; } P;
        P.u[0] = c0.u; P.u[1] = c1.u; P.u[2] = c2.u; P.u[3] = c3.u;
        asm volatile("s_waitcnt lgkmcnt(0)" ::: "memory");
        __builtin_amdgcn_sched_barrier(0);
        union { u32x2 d[2]; f16x8 h; } VA0, VA1;
        VA0.d[0] = t0; VA0.d[1] = t1;
        VA1.d[0] = t2; VA1.d[1] = t3;
        oc0 = __builtin_amdgcn_mfma_f32_16x16x32_f16(VA0.h, P.h, oc0, 0, 0, 0);
        oc1 = __builtin_amdgcn_mfma_f32_16x16x32_f16(VA1.h, P.h, oc1, 0, 0, 0);
    }

    // ---- finalize ----
    l += __shfl_xor(l, 16);
    l += __shfl_xor(l, 32);
    const float inv = 1.0f / l;
    union { f16raw2 h2; uint u; } w00, w01, w10, w11;
    w00.h2 = __builtin_amdgcn_cvt_pkrtz(oc0[0] * inv, oc0[1] * inv);
    w01.h2 = __builtin_amdgcn_cvt_pkrtz(oc0[2] * inv, oc0[3] * inv);
    w10.h2 = __builtin_amdgcn_cvt_pkrtz(oc1[0] * inv, oc1[1] * inv);
    w11.h2 = __builtin_amdgcn_cvt_pkrtz(oc1[2] * inv, oc1[3] * inv);
    ushort* cp = ctx + ((size_t)b * SEQ + (iq - MEMN)) * DIM
               + h * HEAD_DIM + fq4;
    *(uint2*)cp        = (uint2){w00.u, w01.u};
    *(uint2*)(cp + 16) = (uint2){w10.u, w11.u};
}

// ---------------------------------------------------------------------------
extern "C" void kernel_launch(void* const* d_in, const int* in_sizes, int n_in,
                              void* d_out, int out_size, void* d_ws, size_t ws_size,
                              hipStream_t stream) {
    const float* q    = (const float*)d_in[0];
    const float* k    = (const float*)d_in[1];
    const float* v    = (const float*)d_in[2];
    const float* memp = (const float*)d_in[3];
    const float* Wq   = (const float*)d_in[4];
    const float* bq   = (const float*)d_in[5];
    const float* Wk   = (const float*)d_in[6];
    const float* bk   = (const float*)d_in[7];
    const float* Wv   = (const float*)d_in[8];
    const float* bv   = (const float*)d_in[9];
    const float* Wo   = (const float*)d_in[10];
    const float* bo   = (const float*)d_in[11];
    float* out = (float*)d_out;

    const size_t NX = (size_t)MROWS * DIM;
    const size_t NW = (size_t)DIM * DIM;
    const size_t NC = (size_t)OROWS * DIM;

    ushort* p   = (ushort*)d_ws;
    ushort* Qc  = p;            p += NX;
    ushort* Kc  = p;            p += NX;
    ushort* Vc  = p;            p += NX;
    ushort* Fq  = p;            p += NW;
    ushort* Fk  = p;            p += NW;
    ushort* Fv  = p;            p += NW;
    ushort* Fo  = p;            p += NW;
    ushort* Cc  = p;            p += NC;               // ~19 MB total

    dim3 gw(64, 1, 4);
    prep_wfrag<<<gw, 256, 0, stream>>>(Wq, Wk, Wv, Wo, Fq, Fk, Fv, Fo);

    dim3 g1(MROWS / 32, 1, 3);                         // 129 x 1 x 3 = 387 blocks
    gemm_qkv_f<<<g1, 256, 0, stream>>>(q, k, v, memp, Fq, Fk, Fv,
                                       bq, bk, bv, Qc, Kc, Vc);

    dim3 g2(SEQ / QT, NUM_HEADS, BATCH);
    attn_mfma<<<g2, 512, 0, stream>>>(Qc, Kc, Vc, Cc);

    dim3 g3(OROWS / 16, 1, 1);                         // 256 blocks = 1/CU
    gemm_out_f<<<g3, 256, 0, stream>>>(Cc, Fo, bo, out);
}

// Round 16
// 72.661 us; speedup vs baseline: 1.0117x; 1.0117x over previous
//
#include <hip/hip_runtime.h>
#include <hip/hip_bf16.h>
#include <hip/hip_fp16.h>

#define DIM 512
#define NUM_HEADS 16
#define HEAD_DIM 32
#define WHALF 128
#define MEMN 16
#define SEQ 2048
#define BATCH 2
#define T_TOT (SEQ + MEMN)                 // 2064
#define MROWS (BATCH * T_TOT)              // 4128
#define OROWS (BATCH * SEQ)                // 4096
#define QT 128                             // queries per attn block (8 waves)
#define MAXU 416                           // pad32 of max union window (401)
#define KSTR 40                            // sK row stride (halves), 80B
#define VPLANE (MAXU * 16 * 2)             // bytes per sV plane = 13312

typedef _Float16 f16x8 __attribute__((ext_vector_type(8)));
typedef __fp16   f16raw2 __attribute__((ext_vector_type(2)));   // cvt_pkrtz return
typedef float    f32x4 __attribute__((ext_vector_type(4)));
typedef uint     u32x2 __attribute__((ext_vector_type(2)));

#define QSCALE 0.17677669529663687f        // 1/sqrt(32), folded into Wq/bq

// gfx950 LDS transpose read: lane l, elem j <- lds[(l&15) + j*16 + (l>>4)*64]
__device__ __forceinline__ u32x2 tr64(uint addr) {
    u32x2 r;
    asm volatile("ds_read_b64_tr_b16 %0, %1" : "=v"(r) : "v"(addr));
    return r;
}

// ---------------------------------------------------------------------------
// Prep (weights only): Wt[n][k] = (fp16) W[k][n]; Wq pre-scaled by QSCALE.
// ---------------------------------------------------------------------------
__global__ __launch_bounds__(256) void prep_wt(
    const float* __restrict__ Wq, const float* __restrict__ Wk,
    const float* __restrict__ Wv, const float* __restrict__ Wo,
    ushort* __restrict__ Wtq, ushort* __restrict__ Wtk,
    ushort* __restrict__ Wtv, ushort* __restrict__ Wto)
{
    const int w = blockIdx.z;
    const float* W  = w == 0 ? Wq  : (w == 1 ? Wk  : (w == 2 ? Wv  : Wo));
    ushort*     Wt  = w == 0 ? Wtq : (w == 1 ? Wtk : (w == 2 ? Wtv : Wto));
    const float ws  = (w == 0) ? QSCALE : 1.0f;

    __shared__ float sT[64][65];
    const int n0 = (blockIdx.x & 7) * 64;
    const int k0 = (blockIdx.x >> 3) * 64;

    for (int e = threadIdx.x; e < 1024; e += 256) {
        const int r  = e >> 4;
        const int c4 = e & 15;
        const float4 f = *(const float4*)(W + (size_t)(k0 + r) * DIM + n0 + c4 * 4);
        sT[r][c4 * 4 + 0] = f.x;
        sT[r][c4 * 4 + 1] = f.y;
        sT[r][c4 * 4 + 2] = f.z;
        sT[r][c4 * 4 + 3] = f.w;
    }
    __syncthreads();
    for (int u = threadIdx.x; u < 512; u += 256) {
        const int n  = u >> 3;
        const int kg = u & 7;
        union { ushort us[8]; uint4 u4; } o;
        #pragma unroll
        for (int j = 0; j < 8; ++j) {
            _Float16 h = (_Float16)(sT[kg * 8 + j][n] * ws);
            o.us[j] = *(ushort*)&h;
        }
        *(uint4*)(Wt + (size_t)(n0 + n) * DIM + k0 + kg * 8) = o.u4;
    }
}

// ---------------------------------------------------------------------------
// Fused QKV GEMM: 64x128 tile, B in LDS (round-14 proven structure), but
// A staged directly from fp32 inputs (mem-row mapped) with fused fp16 cvt —
// no X fp16 intermediate in global memory.
// ---------------------------------------------------------------------------
__global__ __launch_bounds__(256) void gemm_qkv_fused(
    const float* __restrict__ q, const float* __restrict__ k,
    const float* __restrict__ v, const float* __restrict__ memp,
    const ushort* __restrict__ Wtq, const ushort* __restrict__ Wtk,
    const ushort* __restrict__ Wtv,
    const float* __restrict__ bq, const float* __restrict__ bk,
    const float* __restrict__ bv,
    ushort* __restrict__ Qc, ushort* __restrict__ Kc, ushort* __restrict__ Vc)
{
    const int w = blockIdx.z;
    const float*  X  = w == 0 ? q   : (w == 1 ? k   : v);
    const ushort* Bt = w == 0 ? Wtq : (w == 1 ? Wtk : Wtv);
    const float*  bi = w == 0 ? bq  : (w == 1 ? bk  : bv);
    ushort*       Co = w == 0 ? Qc  : (w == 1 ? Kc  : Vc);
    const float bscale = (w == 0) ? QSCALE : 1.0f;

    __shared__ _Float16 sA[64][72];
    __shared__ _Float16 sB[128][72];

    const int tid  = threadIdx.x;
    const int row0 = blockIdx.x * 64;
    const int col0 = blockIdx.y * 128;
    const int wave = tid >> 6, lane = tid & 63;
    const int wr = wave >> 1, wc = wave & 1;
    const int fr = lane & 15, fq = lane >> 4;

    f32x4 acc[2][4];
    #pragma unroll
    for (int n = 0; n < 4; ++n) {
        const float bb = bi[col0 + wc * 64 + n * 16 + fr] * bscale;
        #pragma unroll
        for (int m = 0; m < 2; ++m) acc[m][n] = (f32x4){bb, bb, bb, bb};
    }

    // Per-thread A staging rows (it=0 -> r0a, it=1 -> r0a+32), fixed cc.
    const int r0a  = tid >> 3;
    const int cc_a = tid & 7;
    const float* srowA[2];
    #pragma unroll
    for (int s = 0; s < 2; ++s) {
        int gr = row0 + r0a + s * 32;
        if (gr >= MROWS) gr = MROWS - 1;
        const int bb_ = gr >= T_TOT ? 1 : 0;
        const int t   = gr - bb_ * T_TOT;
        srowA[s] = (t < MEMN)
            ? (memp + (size_t)t * DIM)
            : (X + ((size_t)bb_ * SEQ + (t - MEMN)) * DIM);
    }

    for (int step = 0; step < 8; ++step) {
        const int k0 = step * 64;
        __syncthreads();
        // A: 2 units/thread, fp32 -> fp16 fused
        #pragma unroll
        for (int s = 0; s < 2; ++s) {
            const float* src = srowA[s] + k0 + cc_a * 8;
            const float4 a0 = ((const float4*)src)[0];
            const float4 a1 = ((const float4*)src)[1];
            union { _Float16 hh[8]; uint4 u4; } o;
            o.hh[0] = (_Float16)a0.x; o.hh[1] = (_Float16)a0.y;
            o.hh[2] = (_Float16)a0.z; o.hh[3] = (_Float16)a0.w;
            o.hh[4] = (_Float16)a1.x; o.hh[5] = (_Float16)a1.y;
            o.hh[6] = (_Float16)a1.z; o.hh[7] = (_Float16)a1.w;
            *(uint4*)&sA[r0a + s * 32][cc_a * 8] = o.u4;
        }
        // B: 4 units/thread (fp16, straight copy)
        #pragma unroll
        for (int it = 0; it < 4; ++it) {
            const int u  = tid + it * 256;      // 0..1023
            const int r  = u >> 3;
            const int cc = u & 7;
            *(uint4*)&sB[r][cc * 8] =
                *(const uint4*)(Bt + (size_t)(col0 + r) * 512 + k0 + cc * 8);
        }
        __syncthreads();
        #pragma unroll
        for (int kk = 0; kk < 2; ++kk) {
            f16x8 a[2], b[4];
            #pragma unroll
            for (int m = 0; m < 2; ++m)
                a[m] = *(const f16x8*)&sA[wr * 32 + m * 16 + fr][kk * 32 + fq * 8];
            #pragma unroll
            for (int n = 0; n < 4; ++n)
                b[n] = *(const f16x8*)&sB[wc * 64 + n * 16 + fr][kk * 32 + fq * 8];
            #pragma unroll
            for (int m = 0; m < 2; ++m)
                #pragma unroll
                for (int n = 0; n < 4; ++n)
                    acc[m][n] = __builtin_amdgcn_mfma_f32_16x16x32_f16(
                        a[m], b[n], acc[m][n], 0, 0, 0);
        }
    }

    #pragma unroll
    for (int m = 0; m < 2; ++m)
        #pragma unroll
        for (int n = 0; n < 4; ++n)
            #pragma unroll
            for (int j = 0; j < 4; ++j) {
                const int row = row0 + wr * 32 + m * 16 + fq * 4 + j;
                const int col = col0 + wc * 64 + n * 16 + fr;
                if (row < MROWS) {
                    _Float16 h = (_Float16)acc[m][n][j];
                    Co[(size_t)row * 512 + col] = *(ushort*)&h;
                }
            }
}

// ---------------------------------------------------------------------------
// Out projection, 64x128 tiles (256 blocks), fp16 A/B in LDS, fp32 out + bias
// (byte-identical structure to round 14).
// ---------------------------------------------------------------------------
__global__ __launch_bounds__(256) void gemm_out64(
    const ushort* __restrict__ A, const ushort* __restrict__ Bt,
    const float* __restrict__ bias, float* __restrict__ C)
{
    __shared__ _Float16 sA[64][72];
    __shared__ _Float16 sB[128][72];

    const int tid  = threadIdx.x;
    const int row0 = blockIdx.x * 64;
    const int col0 = blockIdx.y * 128;
    const int wave = tid >> 6, lane = tid & 63;
    const int wr = wave >> 1, wc = wave & 1;
    const int fr = lane & 15, fq = lane >> 4;

    f32x4 acc[2][4];
    #pragma unroll
    for (int n = 0; n < 4; ++n) {
        const float bb = bias[col0 + wc * 64 + n * 16 + fr];
        #pragma unroll
        for (int m = 0; m < 2; ++m) acc[m][n] = (f32x4){bb, bb, bb, bb};
    }

    for (int k0 = 0; k0 < 512; k0 += 64) {
        __syncthreads();
        #pragma unroll
        for (int it = 0; it < 6; ++it) {
            const int u  = tid + it * 256;      // 0..1535
            const int cc = u & 7;
            if (u < 512) {
                const int r = u >> 3;
                *(uint4*)&sA[r][cc * 8] =
                    *(const uint4*)(A + (size_t)(row0 + r) * 512 + k0 + cc * 8);
            } else {
                const int r = (u - 512) >> 3;
                *(uint4*)&sB[r][cc * 8] =
                    *(const uint4*)(Bt + (size_t)(col0 + r) * 512 + k0 + cc * 8);
            }
        }
        __syncthreads();
        #pragma unroll
        for (int kk = 0; kk < 2; ++kk) {
            f16x8 a[2], b[4];
            #pragma unroll
            for (int m = 0; m < 2; ++m)
                a[m] = *(const f16x8*)&sA[wr * 32 + m * 16 + fr][kk * 32 + fq * 8];
            #pragma unroll
            for (int n = 0; n < 4; ++n)
                b[n] = *(const f16x8*)&sB[wc * 64 + n * 16 + fr][kk * 32 + fq * 8];
            #pragma unroll
            for (int m = 0; m < 2; ++m)
                #pragma unroll
                for (int n = 0; n < 4; ++n)
                    acc[m][n] = __builtin_amdgcn_mfma_f32_16x16x32_f16(
                        a[m], b[n], acc[m][n], 0, 0, 0);
        }
    }

    #pragma unroll
    for (int m = 0; m < 2; ++m)
        #pragma unroll
        for (int n = 0; n < 4; ++n)
            #pragma unroll
            for (int j = 0; j < 4; ++j) {
                const int row = row0 + wr * 32 + m * 16 + fq * 4 + j;
                const int col = col0 + wc * 64 + n * 16 + fr;
                C[(size_t)row * 512 + col] = acc[m][n][j];
            }
}

// ---------------------------------------------------------------------------
// MFMA flash attention (byte-identical to round 14 — verified at 65.3us).
// ---------------------------------------------------------------------------
__global__ __launch_bounds__(512, 4) void attn_mfma(
    const ushort* __restrict__ Q, const ushort* __restrict__ K,
    const ushort* __restrict__ V, ushort* __restrict__ ctx)
{
    const int tid  = threadIdx.x;
    const int tile = blockIdx.x, h = blockIdx.y, b = blockIdx.z;
    const int wave = tid >> 6, lane = tid & 63;
    const int fr = lane & 15, fq = lane >> 4;
    const int fq8 = fq * 8, fq4 = fq * 4;

    const int i0  = MEMN + tile * QT;
    const int klo = max(MEMN, i0 - WHALF);
    const int khi = min(T_TOT - 1, i0 + QT - 1 + WHALF);
    const int total  = MEMN + khi - klo + 1;           // <= 401
    const int ustage = (total + 31) & ~31;             // pad to 32

    __shared__ ushort sK[MAXU][KSTR];                  // 33.3 KiB
    __shared__ ushort sV[2][MAXU][16];                 // 26.0 KiB (two d-planes)

    const size_t hbase = (size_t)b * T_TOT * DIM + (size_t)h * HEAD_DIM;

    // ---- stage K rows (linear quarters) ----
    for (int idx = tid; idx < ustage * 4; idx += 512) {
        const int u = idx >> 2, c = idx & 3;
        uint4 val = {0, 0, 0, 0};
        if (u < total) {
            const int g = (u < MEMN) ? u : klo + u - MEMN;
            val = *(const uint4*)(K + hbase + (size_t)g * DIM + c * 8);
        }
        *(uint4*)&sK[u][c * 8] = val;
    }
    // ---- stage V into two linear planes: plane p = d in [16p, 16p+16) ----
    for (int idx = tid; idx < ustage * 4; idx += 512) {
        const int pl   = (idx >= ustage * 2) ? 1 : 0;
        const int s    = idx - pl * ustage * 2;
        const int u    = s >> 1, half = s & 1;
        uint4 val = {0, 0, 0, 0};
        if (u < total) {
            const int g = (u < MEMN) ? u : klo + u - MEMN;
            val = *(const uint4*)(V + hbase + (size_t)g * DIM + pl * 16 + half * 8);
        }
        *(uint4*)&sV[pl][u][half * 8] = val;
    }

    // ---- Q fragment (pre-scaled): lane holds Q[q=fr][d=fq*8..+7] ----
    const int iq = i0 + wave * 16 + fr;
    const f16x8 qf = *(const f16x8*)(Q + (size_t)(b * T_TOT + iq) * DIM
                                     + h * HEAD_DIM + fq8);

    const int ulo  = max(iq - WHALF - klo, 0) + MEMN;
    const int uhi  = min(iq + WHALF, khi) - klo + MEMN;
    const int span = uhi - ulo;
    const int iw0  = i0 + wave * 16;
    const int ulo_minw = max(iw0 - WHALF - klo, 0) + MEMN;
    const int ulo_maxw = max(iw0 + 15 - WHALF - klo, 0) + MEMN;
    const int uhi_minw = min(iw0 + WHALF, khi) - klo + MEMN;
    const int uhi_maxw = min(iw0 + 15 + WHALF, khi) - klo + MEMN;
    const int glo = max(1, ulo_minw >> 5);
    const int ghi = uhi_maxw >> 5;

    // per-lane tr-read base (byte addr of sV plane0 + 8*lane)
    const uint vlane = (uint)(size_t)(&sV[0][0][0]) + (uint)(lane * 8);

    __syncthreads();

    const float NEGINF = -__builtin_huge_valf();
    float mns = 0.0f;
    float l   = 0.f;
    f32x4 oc0 = {0, 0, 0, 0}, oc1 = {0, 0, 0, 0};

    // ---------------- group 0: mem rows (unmasked) + rows 16-31 ----------------
    {
        const f16x8 kfA = *(const f16x8*)&sK[fr][fq8];
        const f16x8 kfB = *(const f16x8*)&sK[16 + fr][fq8];
        f32x4 sA = {0, 0, 0, 0}, sB = {0, 0, 0, 0};
        sA = __builtin_amdgcn_mfma_f32_16x16x32_f16(kfA, qf, sA, 0, 0, 0);
        sB = __builtin_amdgcn_mfma_f32_16x16x32_f16(kfB, qf, sB, 0, 0, 0);
        const uint vb = vlane;
        u32x2 t0 = tr64(vb), t1 = tr64(vb + 512);
        u32x2 t2 = tr64(vb + VPLANE), t3 = tr64(vb + VPLANE + 512);
        if (!(16 >= ulo_maxw && 31 <= uhi_minw)) {
            #pragma unroll
            for (int j = 0; j < 4; ++j) {
                const uint uu = (uint)(16 + fq4 + j - ulo);
                sB[j] = (uu <= (uint)span) ? sB[j] : NEGINF;
            }
        }
        float mx = fmaxf(fmaxf(fmaxf(sA[0], sA[1]), fmaxf(sA[2], sA[3])),
                         fmaxf(fmaxf(sB[0], sB[1]), fmaxf(sB[2], sB[3])));
        mx = fmaxf(mx, __shfl_xor(mx, 16));
        mx = fmaxf(mx, __shfl_xor(mx, 32));
        if (!__all(mx <= mns)) {
            const float mn2   = fmaxf(mns, mx);
            const float alpha = __expf(mns - mn2);
            l *= alpha;
            #pragma unroll
            for (int j = 0; j < 4; ++j) { oc0[j] *= alpha; oc1[j] *= alpha; }
            mns = mn2;
        }
        const float p0 = __expf(sA[0] - mns), p1 = __expf(sA[1] - mns);
        const float p2 = __expf(sA[2] - mns), p3 = __expf(sA[3] - mns);
        const float p4 = __expf(sB[0] - mns), p5 = __expf(sB[1] - mns);
        const float p6 = __expf(sB[2] - mns), p7 = __expf(sB[3] - mns);
        l += ((p0 + p1) + (p2 + p3)) + ((p4 + p5) + (p6 + p7));
        union { f16raw2 h2; uint u; } c0, c1, c2, c3;
        c0.h2 = __builtin_amdgcn_cvt_pkrtz(p0, p1);
        c1.h2 = __builtin_amdgcn_cvt_pkrtz(p2, p3);
        c2.h2 = __builtin_amdgcn_cvt_pkrtz(p4, p5);
        c3.h2 = __builtin_amdgcn_cvt_pkrtz(p6, p7);
        union { uint u[4]; f16x8 h; } P;
        P.u[0] = c0.u; P.u[1] = c1.u; P.u[2] = c2.u; P.u[3] = c3.u;
        asm volatile("s_waitcnt lgkmcnt(0)" ::: "memory");
        __builtin_amdgcn_sched_barrier(0);
        union { u32x2 d[2]; f16x8 h; } VA0, VA1;
        VA0.d[0] = t0; VA0.d[1] = t1;
        VA1.d[0] = t2; VA1.d[1] = t3;
        oc0 = __builtin_amdgcn_mfma_f32_16x16x32_f16(VA0.h, P.h, oc0, 0, 0, 0);
        oc1 = __builtin_amdgcn_mfma_f32_16x16x32_f16(VA1.h, P.h, oc1, 0, 0, 0);
    }

    // ---------------- window groups, two per iteration ----------------
    int g = glo;
    for (; g + 1 <= ghi; g += 2) {
        const int ua = g * 32, ub2 = ua + 32;
        const f16x8 kf0 = *(const f16x8*)&sK[ua + fr][fq8];
        const f16x8 kf1 = *(const f16x8*)&sK[ua + 16 + fr][fq8];
        const f16x8 kf2 = *(const f16x8*)&sK[ub2 + fr][fq8];
        const f16x8 kf3 = *(const f16x8*)&sK[ub2 + 16 + fr][fq8];
        f32x4 s0 = {0,0,0,0}, s1 = {0,0,0,0}, s2 = {0,0,0,0}, s3 = {0,0,0,0};
        s0 = __builtin_amdgcn_mfma_f32_16x16x32_f16(kf0, qf, s0, 0, 0, 0);
        s1 = __builtin_amdgcn_mfma_f32_16x16x32_f16(kf1, qf, s1, 0, 0, 0);
        s2 = __builtin_amdgcn_mfma_f32_16x16x32_f16(kf2, qf, s2, 0, 0, 0);
        s3 = __builtin_amdgcn_mfma_f32_16x16x32_f16(kf3, qf, s3, 0, 0, 0);
        const uint vb = vlane + (uint)(ua * 32);
        u32x2 ta0 = tr64(vb),          ta1 = tr64(vb + 512);
        u32x2 ta2 = tr64(vb + VPLANE), ta3 = tr64(vb + VPLANE + 512);
        u32x2 tb0 = tr64(vb + 1024),          tb1 = tr64(vb + 1536);
        u32x2 tb2 = tr64(vb + VPLANE + 1024), tb3 = tr64(vb + VPLANE + 1536);
        #pragma unroll
        for (int cch = 0; cch < 4; ++cch) {
            const int base = ua + cch * 16;
            f32x4& sc = cch == 0 ? s0 : (cch == 1 ? s1 : (cch == 2 ? s2 : s3));
            if (!(base >= ulo_maxw && base + 15 <= uhi_minw)) {
                #pragma unroll
                for (int j = 0; j < 4; ++j) {
                    const uint uu = (uint)(base + fq4 + j - ulo);
                    sc[j] = (uu <= (uint)span) ? sc[j] : NEGINF;
                }
            }
        }
        float mxA = fmaxf(fmaxf(fmaxf(s0[0], s0[1]), fmaxf(s0[2], s0[3])),
                          fmaxf(fmaxf(s1[0], s1[1]), fmaxf(s1[2], s1[3])));
        float mxB = fmaxf(fmaxf(fmaxf(s2[0], s2[1]), fmaxf(s2[2], s2[3])),
                          fmaxf(fmaxf(s3[0], s3[1]), fmaxf(s3[2], s3[3])));
        float mx = fmaxf(mxA, mxB);
        mx = fmaxf(mx, __shfl_xor(mx, 16));
        mx = fmaxf(mx, __shfl_xor(mx, 32));
        if (!__all(mx <= mns)) {
            const float mn2   = fmaxf(mns, mx);
            const float alpha = __expf(mns - mn2);
            l *= alpha;
            #pragma unroll
            for (int j = 0; j < 4; ++j) { oc0[j] *= alpha; oc1[j] *= alpha; }
            mns = mn2;
        }
        const float a0 = __expf(s0[0] - mns), a1 = __expf(s0[1] - mns);
        const float a2 = __expf(s0[2] - mns), a3 = __expf(s0[3] - mns);
        const float a4 = __expf(s1[0] - mns), a5 = __expf(s1[1] - mns);
        const float a6 = __expf(s1[2] - mns), a7 = __expf(s1[3] - mns);
        const float b0 = __expf(s2[0] - mns), b1 = __expf(s2[1] - mns);
        const float b2 = __expf(s2[2] - mns), b3 = __expf(s2[3] - mns);
        const float b4 = __expf(s3[0] - mns), b5 = __expf(s3[1] - mns);
        const float b6 = __expf(s3[2] - mns), b7 = __expf(s3[3] - mns);
        l += (((a0 + a1) + (a2 + a3)) + ((a4 + a5) + (a6 + a7)))
           + (((b0 + b1) + (b2 + b3)) + ((b4 + b5) + (b6 + b7)));
        union { f16raw2 h2; uint u; } d0, d1, d2, d3, e0, e1, e2, e3;
        d0.h2 = __builtin_amdgcn_cvt_pkrtz(a0, a1);
        d1.h2 = __builtin_amdgcn_cvt_pkrtz(a2, a3);
        d2.h2 = __builtin_amdgcn_cvt_pkrtz(a4, a5);
        d3.h2 = __builtin_amdgcn_cvt_pkrtz(a6, a7);
        e0.h2 = __builtin_amdgcn_cvt_pkrtz(b0, b1);
        e1.h2 = __builtin_amdgcn_cvt_pkrtz(b2, b3);
        e2.h2 = __builtin_amdgcn_cvt_pkrtz(b4, b5);
        e3.h2 = __builtin_amdgcn_cvt_pkrtz(b6, b7);
        union { uint u[4]; f16x8 h; } P0, P1;
        P0.u[0] = d0.u; P0.u[1] = d1.u; P0.u[2] = d2.u; P0.u[3] = d3.u;
        P1.u[0] = e0.u; P1.u[1] = e1.u; P1.u[2] = e2.u; P1.u[3] = e3.u;
        asm volatile("s_waitcnt lgkmcnt(0)" ::: "memory");
        __builtin_amdgcn_sched_barrier(0);
        union { u32x2 d[2]; f16x8 h; } A0, A1, B0, B1;
        A0.d[0] = ta0; A0.d[1] = ta1;
        A1.d[0] = ta2; A1.d[1] = ta3;
        B0.d[0] = tb0; B0.d[1] = tb1;
        B1.d[0] = tb2; B1.d[1] = tb3;
        oc0 = __builtin_amdgcn_mfma_f32_16x16x32_f16(A0.h, P0.h, oc0, 0, 0, 0);
        oc1 = __builtin_amdgcn_mfma_f32_16x16x32_f16(A1.h, P0.h, oc1, 0, 0, 0);
        oc0 = __builtin_amdgcn_mfma_f32_16x16x32_f16(B0.h, P1.h, oc0, 0, 0, 0);
        oc1 = __builtin_amdgcn_mfma_f32_16x16x32_f16(B1.h, P1.h, oc1, 0, 0, 0);
    }
    // odd tail group
    if (g <= ghi) {
        const int ua = g * 32;
        const f16x8 kf0 = *(const f16x8*)&sK[ua + fr][fq8];
        const f16x8 kf1 = *(const f16x8*)&sK[ua + 16 + fr][fq8];
        f32x4 s0 = {0,0,0,0}, s1 = {0,0,0,0};
        s0 = __builtin_amdgcn_mfma_f32_16x16x32_f16(kf0, qf, s0, 0, 0, 0);
        s1 = __builtin_amdgcn_mfma_f32_16x16x32_f16(kf1, qf, s1, 0, 0, 0);
        const uint vb = vlane + (uint)(ua * 32);
        u32x2 t0 = tr64(vb),          t1 = tr64(vb + 512);
        u32x2 t2 = tr64(vb + VPLANE), t3 = tr64(vb + VPLANE + 512);
        #pragma unroll
        for (int cch = 0; cch < 2; ++cch) {
            const int base = ua + cch * 16;
            f32x4& sc = cch == 0 ? s0 : s1;
            if (!(base >= ulo_maxw && base + 15 <= uhi_minw)) {
                #pragma unroll
                for (int j = 0; j < 4; ++j) {
                    const uint uu = (uint)(base + fq4 + j - ulo);
                    sc[j] = (uu <= (uint)span) ? sc[j] : NEGINF;
                }
            }
        }
        float mx = fmaxf(fmaxf(fmaxf(s0[0], s0[1]), fmaxf(s0[2], s0[3])),
                         fmaxf(fmaxf(s1[0], s1[1]), fmaxf(s1[2], s1[3])));
        mx = fmaxf(mx, __shfl_xor(mx, 16));
        mx = fmaxf(mx, __shfl_xor(mx, 32));
        if (!__all(mx <= mns)) {
            const float mn2   = fmaxf(mns, mx);
            const float alpha = __expf(mns - mn2);
            l *= alpha;
            #pragma unroll
            for (int j = 0; j < 4; ++j) { oc0[j] *= alpha; oc1[j] *= alpha; }
            mns = mn2;
        }
        const float p0 = __expf(s0[0] - mns), p1 = __expf(s0[1] - mns);
        const float p2 = __expf(s0[2] - mns), p3 = __expf(s0[3] - mns);
        const float p4 = __expf(s1[0] - mns), p5 = __expf(s1[1] - mns);
        const float p6 = __expf(s1[2] - mns), p7 = __expf(s1[3] - mns);
        l += ((p0 + p1) + (p2 + p3)) + ((p4 + p5) + (p6 + p7));
        union { f16raw2 h2; uint u; } c0, c1, c2, c3;
        c0.h2 = __builtin_amdgcn_cvt_pkrtz(p0, p1);
        c1.h2 = __builtin_amdgcn_cvt_pkrtz(p2, p3);
        c2.h2 = __builtin_amdgcn_cvt_pkrtz(p4, p5);
        c3.h2 = __builtin_amdgcn_cvt_pkrtz(p6, p7);
        union { uint u[4]; f16x8 h; } P;
        P.u[0] = c0.u; P.u[1] = c1.u; P.u[2] = c2.u; P.u[3] = c3.u;
        asm volatile("s_waitcnt lgkmcnt(0)" ::: "memory");
        __builtin_amdgcn_sched_barrier(0);
        union { u32x2 d[2]; f16x8 h; } VA0, VA1;
        VA0.d[0] = t0; VA0.d[1] = t1;
        VA1.d[0] = t2; VA1.d[1] = t3;
        oc0 = __builtin_amdgcn_mfma_f32_16x16x32_f16(VA0.h, P.h, oc0, 0, 0, 0);
        oc1 = __builtin_amdgcn_mfma_f32_16x16x32_f16(VA1.h, P.h, oc1, 0, 0, 0);
    }

    // ---- finalize ----
    l += __shfl_xor(l, 16);
    l += __shfl_xor(l, 32);
    const float inv = 1.0f / l;
    union { f16raw2 h2; uint u; } w00, w01, w10, w11;
    w00.h2 = __builtin_amdgcn_cvt_pkrtz(oc0[0] * inv, oc0[1] * inv);
    w01.h2 = __builtin_amdgcn_cvt_pkrtz(oc0[2] * inv, oc0[3] * inv);
    w10.h2 = __builtin_amdgcn_cvt_pkrtz(oc1[0] * inv, oc1[1] * inv);
    w11.h2 = __builtin_amdgcn_cvt_pkrtz(oc1[2] * inv, oc1[3] * inv);
    ushort* cp = ctx + ((size_t)b * SEQ + (iq - MEMN)) * DIM
               + h * HEAD_DIM + fq4;
    *(uint2*)cp        = (uint2){w00.u, w01.u};
    *(uint2*)(cp + 16) = (uint2){w10.u, w11.u};
}

// ---------------------------------------------------------------------------
extern "C" void kernel_launch(void* const* d_in, const int* in_sizes, int n_in,
                              void* d_out, int out_size, void* d_ws, size_t ws_size,
                              hipStream_t stream) {
    const float* q    = (const float*)d_in[0];
    const float* k    = (const float*)d_in[1];
    const float* v    = (const float*)d_in[2];
    const float* memp = (const float*)d_in[3];
    const float* Wq   = (const float*)d_in[4];
    const float* bq   = (const float*)d_in[5];
    const float* Wk   = (const float*)d_in[6];
    const float* bk   = (const float*)d_in[7];
    const float* Wv   = (const float*)d_in[8];
    const float* bv   = (const float*)d_in[9];
    const float* Wo   = (const float*)d_in[10];
    const float* bo   = (const float*)d_in[11];
    float* out = (float*)d_out;

    const size_t NX = (size_t)MROWS * DIM;
    const size_t NW = (size_t)DIM * DIM;
    const size_t NC = (size_t)OROWS * DIM;

    ushort* p   = (ushort*)d_ws;
    ushort* Qc  = p;            p += NX;
    ushort* Kc  = p;            p += NX;
    ushort* Vc  = p;            p += NX;
    ushort* Wtq = p;            p += NW;
    ushort* Wtk = p;            p += NW;
    ushort* Wtv = p;            p += NW;
    ushort* Wto = p;            p += NW;
    ushort* Cc  = p;            p += NC;               // ~19 MB total

    dim3 gw(64, 1, 4);
    prep_wt<<<gw, 256, 0, stream>>>(Wq, Wk, Wv, Wo, Wtq, Wtk, Wtv, Wto);

    dim3 g1((MROWS + 63) / 64, 4, 3);                  // 65 x 4 x 3 = 780 blocks
    gemm_qkv_fused<<<g1, 256, 0, stream>>>(q, k, v, memp, Wtq, Wtk, Wtv,
                                           bq, bk, bv, Qc, Kc, Vc);

    dim3 g2(SEQ / QT, NUM_HEADS, BATCH);
    attn_mfma<<<g2, 512, 0, stream>>>(Qc, Kc, Vc, Cc);

    dim3 g3(OROWS / 64, 4, 1);                         // 64 x 4 = 256 blocks
    gemm_out64<<<g3, 256, 0, stream>>>(Cc, Wto, bo, out);
}

// Round 19
// 65.516 us; speedup vs baseline: 1.1221x; 1.1091x over previous
//
#include <hip/hip_runtime.h>
#include <hip/hip_bf16.h>
#include <hip/hip_fp16.h>

#define DIM 512
#define NUM_HEADS 16
#define HEAD_DIM 32
#define WHALF 128
#define MEMN 16
#define SEQ 2048
#define BATCH 2
#define T_TOT (SEQ + MEMN)                 // 2064
#define MROWS (BATCH * T_TOT)              // 4128
#define OROWS (BATCH * SEQ)                // 4096
#define QT 128                             // queries per attn block (8 waves)
#define MAXU 416                           // pad32 of max union window (401)
#define KSTR 40                            // sK row stride (halves), 80B
#define VPLANE (MAXU * 16 * 2)             // bytes per sV plane = 13312

typedef _Float16 f16x8 __attribute__((ext_vector_type(8)));
typedef __fp16   f16raw2 __attribute__((ext_vector_type(2)));   // cvt_pkrtz return
typedef float    f32x4 __attribute__((ext_vector_type(4)));
typedef uint     u32x2 __attribute__((ext_vector_type(2)));

#define QSCALE 0.17677669529663687f        // 1/sqrt(32), folded into Wq/bq

// gfx950 LDS transpose read: lane l, elem j <- lds[(l&15) + j*16 + (l>>4)*64]
__device__ __forceinline__ u32x2 tr64(uint addr) {
    u32x2 r;
    asm volatile("ds_read_b64_tr_b16 %0, %1" : "=v"(r) : "v"(addr));
    return r;
}

// ---------------------------------------------------------------------------
// Merged prep: z in [0,3): fp16 X matrices (16 elems/thread); z in [3,7):
// Wt[n][k] = W[k][n]. Wq pre-scaled by QSCALE.
// ---------------------------------------------------------------------------
__global__ __launch_bounds__(256) void prep_cvt(
    const float* __restrict__ q, const float* __restrict__ k,
    const float* __restrict__ v, const float* __restrict__ memp,
    const float* __restrict__ Wq, const float* __restrict__ Wk,
    const float* __restrict__ Wv, const float* __restrict__ Wo,
    ushort* __restrict__ Xq, ushort* __restrict__ Xk, ushort* __restrict__ Xv,
    ushort* __restrict__ Wtq, ushort* __restrict__ Wtk,
    ushort* __restrict__ Wtv, ushort* __restrict__ Wto)
{
    const int z = blockIdx.z;
    if (z < 3) {
        const float* X = z == 0 ? q : (z == 1 ? k : v);
        ushort*     Xc = z == 0 ? Xq : (z == 1 ? Xk : Xv);
        const int gid  = blockIdx.x * 256 + threadIdx.x;
        const int base = gid * 16;
        if (base >= MROWS * DIM) return;
        const int row = base >> 9;
        const int c   = base & 511;
        const int b   = row / T_TOT;
        const int t   = row - b * T_TOT;
        const float* src = (t < MEMN)
            ? (memp + (size_t)t * DIM + c)
            : (X + ((size_t)b * SEQ + (t - MEMN)) * DIM + c);
        #pragma unroll
        for (int half = 0; half < 2; ++half) {
            const float4 a0 = ((const float4*)src)[half * 2 + 0];
            const float4 a1 = ((const float4*)src)[half * 2 + 1];
            union { _Float16 hh[8]; uint4 u4; } o;
            o.hh[0] = (_Float16)a0.x; o.hh[1] = (_Float16)a0.y;
            o.hh[2] = (_Float16)a0.z; o.hh[3] = (_Float16)a0.w;
            o.hh[4] = (_Float16)a1.x; o.hh[5] = (_Float16)a1.y;
            o.hh[6] = (_Float16)a1.z; o.hh[7] = (_Float16)a1.w;
            *(uint4*)(Xc + (size_t)row * DIM + c + half * 8) = o.u4;
        }
        return;
    }
    if (blockIdx.x >= 64) return;
    const int w = z - 3;
    const float* W  = w == 0 ? Wq  : (w == 1 ? Wk  : (w == 2 ? Wv  : Wo));
    ushort*     Wt  = w == 0 ? Wtq : (w == 1 ? Wtk : (w == 2 ? Wtv : Wto));
    const float ws  = (w == 0) ? QSCALE : 1.0f;

    __shared__ float sT[64][65];
    const int n0 = (blockIdx.x & 7) * 64;
    const int k0 = (blockIdx.x >> 3) * 64;

    for (int e = threadIdx.x; e < 1024; e += 256) {
        const int r  = e >> 4;
        const int c4 = e & 15;
        const float4 f = *(const float4*)(W + (size_t)(k0 + r) * DIM + n0 + c4 * 4);
        sT[r][c4 * 4 + 0] = f.x;
        sT[r][c4 * 4 + 1] = f.y;
        sT[r][c4 * 4 + 2] = f.z;
        sT[r][c4 * 4 + 3] = f.w;
    }
    __syncthreads();
    for (int u = threadIdx.x; u < 512; u += 256) {
        const int n  = u >> 3;
        const int kg = u & 7;
        union { ushort us[8]; uint4 u4; } o;
        #pragma unroll
        for (int j = 0; j < 8; ++j) {
            _Float16 h = (_Float16)(sT[kg * 8 + j][n] * ws);
            o.us[j] = *(ushort*)&h;
        }
        *(uint4*)(Wt + (size_t)(n0 + n) * DIM + k0 + kg * 8) = o.u4;
    }
}

// ---------------------------------------------------------------------------
// fp16 MFMA GEMM, 64x128 tile (round-14 proven): C = A @ Wt^T + bias*bscale
// ---------------------------------------------------------------------------
template<bool OUT_HALF>
__device__ __forceinline__ void gemm_body64(
    const ushort* __restrict__ A, const ushort* __restrict__ Bt,
    const float* __restrict__ bias, float bscale, void* __restrict__ C, int M)
{
    __shared__ _Float16 sA[64][72];
    __shared__ _Float16 sB[128][72];

    const int tid  = threadIdx.x;
    const int row0 = blockIdx.x * 64;
    const int col0 = blockIdx.y * 128;
    const int wave = tid >> 6, lane = tid & 63;
    const int wr = wave >> 1, wc = wave & 1;
    const int fr = lane & 15, fq = lane >> 4;

    f32x4 acc[2][4];
    #pragma unroll
    for (int n = 0; n < 4; ++n) {
        const float bb = bias[col0 + wc * 64 + n * 16 + fr] * bscale;
        #pragma unroll
        for (int m = 0; m < 2; ++m) acc[m][n] = (f32x4){bb, bb, bb, bb};
    }

    for (int k0 = 0; k0 < 512; k0 += 64) {
        __syncthreads();
        #pragma unroll
        for (int it = 0; it < 6; ++it) {
            const int u  = tid + it * 256;      // 0..1535
            const int cc = u & 7;
            if (u < 512) {
                const int r = u >> 3;
                int gr = row0 + r; if (gr >= M) gr = M - 1;
                *(uint4*)&sA[r][cc * 8] =
                    *(const uint4*)(A + (size_t)gr * 512 + k0 + cc * 8);
            } else {
                const int r = (u - 512) >> 3;
                *(uint4*)&sB[r][cc * 8] =
                    *(const uint4*)(Bt + (size_t)(col0 + r) * 512 + k0 + cc * 8);
            }
        }
        __syncthreads();
        #pragma unroll
        for (int kk = 0; kk < 2; ++kk) {
            f16x8 a[2], b[4];
            #pragma unroll
            for (int m = 0; m < 2; ++m)
                a[m] = *(const f16x8*)&sA[wr * 32 + m * 16 + fr][kk * 32 + fq * 8];
            #pragma unroll
            for (int n = 0; n < 4; ++n)
                b[n] = *(const f16x8*)&sB[wc * 64 + n * 16 + fr][kk * 32 + fq * 8];
            #pragma unroll
            for (int m = 0; m < 2; ++m)
                #pragma unroll
                for (int n = 0; n < 4; ++n)
                    acc[m][n] = __builtin_amdgcn_mfma_f32_16x16x32_f16(
                        a[m], b[n], acc[m][n], 0, 0, 0);
        }
    }

    #pragma unroll
    for (int m = 0; m < 2; ++m)
        #pragma unroll
        for (int n = 0; n < 4; ++n)
            #pragma unroll
            for (int j = 0; j < 4; ++j) {
                const int row = row0 + wr * 32 + m * 16 + fq * 4 + j;
                const int col = col0 + wc * 64 + n * 16 + fr;
                if (row < M) {
                    if (OUT_HALF) {
                        _Float16 h = (_Float16)acc[m][n][j];
                        ((ushort*)C)[(size_t)row * 512 + col] = *(ushort*)&h;
                    } else {
                        ((float*)C)[(size_t)row * 512 + col] = acc[m][n][j];
                    }
                }
            }
}

__global__ __launch_bounds__(256) void gemm_qkv(
    const ushort* __restrict__ Xq, const ushort* __restrict__ Xk,
    const ushort* __restrict__ Xv,
    const ushort* __restrict__ Wtq, const ushort* __restrict__ Wtk,
    const ushort* __restrict__ Wtv,
    const float* __restrict__ bq, const float* __restrict__ bk,
    const float* __restrict__ bv,
    ushort* __restrict__ Qc, ushort* __restrict__ Kc, ushort* __restrict__ Vc)
{
    const int w = blockIdx.z;
    const ushort* A  = w == 0 ? Xq  : (w == 1 ? Xk  : Xv);
    const ushort* Bt = w == 0 ? Wtq : (w == 1 ? Wtk : Wtv);
    const float*  bi = w == 0 ? bq  : (w == 1 ? bk  : bv);
    ushort*       Cc = w == 0 ? Qc  : (w == 1 ? Kc  : Vc);
    gemm_body64<true>(A, Bt, bi, (w == 0) ? QSCALE : 1.0f, Cc, MROWS);
}

__global__ __launch_bounds__(256) void gemm_out64(
    const ushort* __restrict__ A, const ushort* __restrict__ Bt,
    const float* __restrict__ bias, float* __restrict__ C)
{
    gemm_body64<false>(A, Bt, bias, 1.0f, C, OROWS);
}

// ---------------------------------------------------------------------------
// MFMA flash attention (byte-identical to round 14 — verified at 65.3us).
// ---------------------------------------------------------------------------
__global__ __launch_bounds__(512, 4) void attn_mfma(
    const ushort* __restrict__ Q, const ushort* __restrict__ K,
    const ushort* __restrict__ V, ushort* __restrict__ ctx)
{
    const int tid  = threadIdx.x;
    const int tile = blockIdx.x, h = blockIdx.y, b = blockIdx.z;
    const int wave = tid >> 6, lane = tid & 63;
    const int fr = lane & 15, fq = lane >> 4;
    const int fq8 = fq * 8, fq4 = fq * 4;

    const int i0  = MEMN + tile * QT;
    const int klo = max(MEMN, i0 - WHALF);
    const int khi = min(T_TOT - 1, i0 + QT - 1 + WHALF);
    const int total  = MEMN + khi - klo + 1;           // <= 401
    const int ustage = (total + 31) & ~31;             // pad to 32

    __shared__ ushort sK[MAXU][KSTR];                  // 33.3 KiB
    __shared__ ushort sV[2][MAXU][16];                 // 26.0 KiB (two d-planes)

    const size_t hbase = (size_t)b * T_TOT * DIM + (size_t)h * HEAD_DIM;

    // ---- stage K rows (linear quarters) ----
    for (int idx = tid; idx < ustage * 4; idx += 512) {
        const int u = idx >> 2, c = idx & 3;
        uint4 val = {0, 0, 0, 0};
        if (u < total) {
            const int g = (u < MEMN) ? u : klo + u - MEMN;
            val = *(const uint4*)(K + hbase + (size_t)g * DIM + c * 8);
        }
        *(uint4*)&sK[u][c * 8] = val;
    }
    // ---- stage V into two linear planes: plane p = d in [16p, 16p+16) ----
    for (int idx = tid; idx < ustage * 4; idx += 512) {
        const int pl   = (idx >= ustage * 2) ? 1 : 0;
        const int s    = idx - pl * ustage * 2;
        const int u    = s >> 1, half = s & 1;
        uint4 val = {0, 0, 0, 0};
        if (u < total) {
            const int g = (u < MEMN) ? u : klo + u - MEMN;
            val = *(const uint4*)(V + hbase + (size_t)g * DIM + pl * 16 + half * 8);
        }
        *(uint4*)&sV[pl][u][half * 8] = val;
    }

    // ---- Q fragment (pre-scaled): lane holds Q[q=fr][d=fq*8..+7] ----
    const int iq = i0 + wave * 16 + fr;
    const f16x8 qf = *(const f16x8*)(Q + (size_t)(b * T_TOT + iq) * DIM
                                     + h * HEAD_DIM + fq8);

    const int ulo  = max(iq - WHALF - klo, 0) + MEMN;
    const int uhi  = min(iq + WHALF, khi) - klo + MEMN;
    const int span = uhi - ulo;
    const int iw0  = i0 + wave * 16;
    const int ulo_minw = max(iw0 - WHALF - klo, 0) + MEMN;
    const int ulo_maxw = max(iw0 + 15 - WHALF - klo, 0) + MEMN;
    const int uhi_minw = min(iw0 + WHALF, khi) - klo + MEMN;
    const int uhi_maxw = min(iw0 + 15 + WHALF, khi) - klo + MEMN;
    const int glo = max(1, ulo_minw >> 5);
    const int ghi = uhi_maxw >> 5;

    // per-lane tr-read base (byte addr of sV plane0 + 8*lane)
    const uint vlane = (uint)(size_t)(&sV[0][0][0]) + (uint)(lane * 8);

    __syncthreads();

    const float NEGINF = -__builtin_huge_valf();
    float mns = 0.0f;
    float l   = 0.f;
    f32x4 oc0 = {0, 0, 0, 0}, oc1 = {0, 0, 0, 0};

    // ---------------- group 0: mem rows (unmasked) + rows 16-31 ----------------
    {
        const f16x8 kfA = *(const f16x8*)&sK[fr][fq8];
        const f16x8 kfB = *(const f16x8*)&sK[16 + fr][fq8];
        f32x4 sA = {0, 0, 0, 0}, sB = {0, 0, 0, 0};
        sA = __builtin_amdgcn_mfma_f32_16x16x32_f16(kfA, qf, sA, 0, 0, 0);
        sB = __builtin_amdgcn_mfma_f32_16x16x32_f16(kfB, qf, sB, 0, 0, 0);
        const uint vb = vlane;
        u32x2 t0 = tr64(vb), t1 = tr64(vb + 512);
        u32x2 t2 = tr64(vb + VPLANE), t3 = tr64(vb + VPLANE + 512);
        if (!(16 >= ulo_maxw && 31 <= uhi_minw)) {
            #pragma unroll
            for (int j = 0; j < 4; ++j) {
                const uint uu = (uint)(16 + fq4 + j - ulo);
                sB[j] = (uu <= (uint)span) ? sB[j] : NEGINF;
            }
        }
        float mx = fmaxf(fmaxf(fmaxf(sA[0], sA[1]), fmaxf(sA[2], sA[3])),
                         fmaxf(fmaxf(sB[0], sB[1]), fmaxf(sB[2], sB[3])));
        mx = fmaxf(mx, __shfl_xor(mx, 16));
        mx = fmaxf(mx, __shfl_xor(mx, 32));
        if (!__all(mx <= mns)) {
            const float mn2   = fmaxf(mns, mx);
            const float alpha = __expf(mns - mn2);
            l *= alpha;
            #pragma unroll
            for (int j = 0; j < 4; ++j) { oc0[j] *= alpha; oc1[j] *= alpha; }
            mns = mn2;
        }
        const float p0 = __expf(sA[0] - mns), p1 = __expf(sA[1] - mns);
        const float p2 = __expf(sA[2] - mns), p3 = __expf(sA[3] - mns);
        const float p4 = __expf(sB[0] - mns), p5 = __expf(sB[1] - mns);
        const float p6 = __expf(sB[2] - mns), p7 = __expf(sB[3] - mns);
        l += ((p0 + p1) + (p2 + p3)) + ((p4 + p5) + (p6 + p7));
        union { f16raw2 h2; uint u; } c0, c1, c2, c3;
        c0.h2 = __builtin_amdgcn_cvt_pkrtz(p0, p1);
        c1.h2 = __builtin_amdgcn_cvt_pkrtz(p2, p3);
        c2.h2 = __builtin_amdgcn_cvt_pkrtz(p4, p5);
        c3.h2 = __builtin_amdgcn_cvt_pkrtz(p6, p7);
        union { uint u[4]; f16x8 h; } P;
        P.u[0] = c0.u; P.u[1] = c1.u; P.u[2] = c2.u; P.u[3] = c3.u;
        asm volatile("s_waitcnt lgkmcnt(0)" ::: "memory");
        __builtin_amdgcn_sched_barrier(0);
        union { u32x2 d[2]; f16x8 h; } VA0, VA1;
        VA0.d[0] = t0; VA0.d[1] = t1;
        VA1.d[0] = t2; VA1.d[1] = t3;
        oc0 = __builtin_amdgcn_mfma_f32_16x16x32_f16(VA0.h, P.h, oc0, 0, 0, 0);
        oc1 = __builtin_amdgcn_mfma_f32_16x16x32_f16(VA1.h, P.h, oc1, 0, 0, 0);
    }

    // ---------------- window groups, two per iteration ----------------
    int g = glo;
    for (; g + 1 <= ghi; g += 2) {
        const int ua = g * 32, ub2 = ua + 32;
        const f16x8 kf0 = *(const f16x8*)&sK[ua + fr][fq8];
        const f16x8 kf1 = *(const f16x8*)&sK[ua + 16 + fr][fq8];
        const f16x8 kf2 = *(const f16x8*)&sK[ub2 + fr][fq8];
        const f16x8 kf3 = *(const f16x8*)&sK[ub2 + 16 + fr][fq8];
        f32x4 s0 = {0,0,0,0}, s1 = {0,0,0,0}, s2 = {0,0,0,0}, s3 = {0,0,0,0};
        s0 = __builtin_amdgcn_mfma_f32_16x16x32_f16(kf0, qf, s0, 0, 0, 0);
        s1 = __builtin_amdgcn_mfma_f32_16x16x32_f16(kf1, qf, s1, 0, 0, 0);
        s2 = __builtin_amdgcn_mfma_f32_16x16x32_f16(kf2, qf, s2, 0, 0, 0);
        s3 = __builtin_amdgcn_mfma_f32_16x16x32_f16(kf3, qf, s3, 0, 0, 0);
        const uint vb = vlane + (uint)(ua * 32);
        u32x2 ta0 = tr64(vb),          ta1 = tr64(vb + 512);
        u32x2 ta2 = tr64(vb + VPLANE), ta3 = tr64(vb + VPLANE + 512);
        u32x2 tb0 = tr64(vb + 1024),          tb1 = tr64(vb + 1536);
        u32x2 tb2 = tr64(vb + VPLANE + 1024), tb3 = tr64(vb + VPLANE + 1536);
        #pragma unroll
        for (int cch = 0; cch < 4; ++cch) {
            const int base = ua + cch * 16;
            f32x4& sc = cch == 0 ? s0 : (cch == 1 ? s1 : (cch == 2 ? s2 : s3));
            if (!(base >= ulo_maxw && base + 15 <= uhi_minw)) {
                #pragma unroll
                for (int j = 0; j < 4; ++j) {
                    const uint uu = (uint)(base + fq4 + j - ulo);
                    sc[j] = (uu <= (uint)span) ? sc[j] : NEGINF;
                }
            }
        }
        float mxA = fmaxf(fmaxf(fmaxf(s0[0], s0[1]), fmaxf(s0[2], s0[3])),
                          fmaxf(fmaxf(s1[0], s1[1]), fmaxf(s1[2], s1[3])));
        float mxB = fmaxf(fmaxf(fmaxf(s2[0], s2[1]), fmaxf(s2[2], s2[3])),
                          fmaxf(fmaxf(s3[0], s3[1]), fmaxf(s3[2], s3[3])));
        float mx = fmaxf(mxA, mxB);
        mx = fmaxf(mx, __shfl_xor(mx, 16));
        mx = fmaxf(mx, __shfl_xor(mx, 32));
        if (!__all(mx <= mns)) {
            const float mn2   = fmaxf(mns, mx);
            const float alpha = __expf(mns - mn2);
            l *= alpha;
            #pragma unroll
            for (int j = 0; j < 4; ++j) { oc0[j] *= alpha; oc1[j] *= alpha; }
            mns = mn2;
        }
        const float a0 = __expf(s0[0] - mns), a1 = __expf(s0[1] - mns);
        const float a2 = __expf(s0[2] - mns), a3 = __expf(s0[3] - mns);
        const float a4 = __expf(s1[0] - mns), a5 = __expf(s1[1] - mns);
        const float a6 = __expf(s1[2] - mns), a7 = __expf(s1[3] - mns);
        const float b0 = __expf(s2[0] - mns), b1 = __expf(s2[1] - mns);
        const float b2 = __expf(s2[2] - mns), b3 = __expf(s2[3] - mns);
        const float b4 = __expf(s3[0] - mns), b5 = __expf(s3[1] - mns);
        const float b6 = __expf(s3[2] - mns), b7 = __expf(s3[3] - mns);
        l += (((a0 + a1) + (a2 + a3)) + ((a4 + a5) + (a6 + a7)))
           + (((b0 + b1) + (b2 + b3)) + ((b4 + b5) + (b6 + b7)));
        union { f16raw2 h2; uint u; } d0, d1, d2, d3, e0, e1, e2, e3;
        d0.h2 = __builtin_amdgcn_cvt_pkrtz(a0, a1);
        d1.h2 = __builtin_amdgcn_cvt_pkrtz(a2, a3);
        d2.h2 = __builtin_amdgcn_cvt_pkrtz(a4, a5);
        d3.h2 = __builtin_amdgcn_cvt_pkrtz(a6, a7);
        e0.h2 = __builtin_amdgcn_cvt_pkrtz(b0, b1);
        e1.h2 = __builtin_amdgcn_cvt_pkrtz(b2, b3);
        e2.h2 = __builtin_amdgcn_cvt_pkrtz(b4, b5);
        e3.h2 = __builtin_amdgcn_cvt_pkrtz(b6, b7);
        union { uint u[4]; f16x8 h; } P0, P1;
        P0.u[0] = d0.u; P0.u[1] = d1.u; P0.u[2] = d2.u; P0.u[3] = d3.u;
        P1.u[0] = e0.u; P1.u[1] = e1.u; P1.u[2] = e2.u; P1.u[3] = e3.u;
        asm volatile("s_waitcnt lgkmcnt(0)" ::: "memory");
        __builtin_amdgcn_sched_barrier(0);
        union { u32x2 d[2]; f16x8 h; } A0, A1, B0, B1;
        A0.d[0] = ta0; A0.d[1] = ta1;
        A1.d[0] = ta2; A1.d[1] = ta3;
        B0.d[0] = tb0; B0.d[1] = tb1;
        B1.d[0] = tb2; B1.d[1] = tb3;
        oc0 = __builtin_amdgcn_mfma_f32_16x16x32_f16(A0.h, P0.h, oc0, 0, 0, 0);
        oc1 = __builtin_amdgcn_mfma_f32_16x16x32_f16(A1.h, P0.h, oc1, 0, 0, 0);
        oc0 = __builtin_amdgcn_mfma_f32_16x16x32_f16(B0.h, P1.h, oc0, 0, 0, 0);
        oc1 = __builtin_amdgcn_mfma_f32_16x16x32_f16(B1.h, P1.h, oc1, 0, 0, 0);
    }
    // odd tail group
    if (g <= ghi) {
        const int ua = g * 32;
        const f16x8 kf0 = *(const f16x8*)&sK[ua + fr][fq8];
        const f16x8 kf1 = *(const f16x8*)&sK[ua + 16 + fr][fq8];
        f32x4 s0 = {0,0,0,0}, s1 = {0,0,0,0};
        s0 = __builtin_amdgcn_mfma_f32_16x16x32_f16(kf0, qf, s0, 0, 0, 0);
        s1 = __builtin_amdgcn_mfma_f32_16x16x32_f16(kf1, qf, s1, 0, 0, 0);
        const uint vb = vlane + (uint)(ua * 32);
        u32x2 t0 = tr64(vb),          t1 = tr64(vb + 512);
        u32x2 t2 = tr64(vb + VPLANE), t3 = tr64(vb + VPLANE + 512);
        #pragma unroll
        for (int cch = 0; cch < 2; ++cch) {
            const int base = ua + cch * 16;
            f32x4& sc = cch == 0 ? s0 : s1;
            if (!(base >= ulo_maxw && base + 15 <= uhi_minw)) {
                #pragma unroll
                for (int j = 0; j < 4; ++j) {
                    const uint uu = (uint)(base + fq4 + j - ulo);
                    sc[j] = (uu <= (uint)span) ? sc[j] : NEGINF;
                }
            }
        }
        float mx = fmaxf(fmaxf(fmaxf(s0[0], s0[1]), fmaxf(s0[2], s0[3])),
                         fmaxf(fmaxf(s1[0], s1[1]), fmaxf(s1[2], s1[3])));
        mx = fmaxf(mx, __shfl_xor(mx, 16));
        mx = fmaxf(mx, __shfl_xor(mx, 32));
        if (!__all(mx <= mns)) {
            const float mn2   = fmaxf(mns, mx);
            const float alpha = __expf(mns - mn2);
            l *= alpha;
            #pragma unroll
            for (int j = 0; j < 4; ++j) { oc0[j] *= alpha; oc1[j] *= alpha; }
            mns = mn2;
        }
        const float p0 = __expf(s0[0] - mns), p1 = __expf(s0[1] - mns);
        const float p2 = __expf(s0[2] - mns), p3 = __expf(s0[3] - mns);
        const float p4 = __expf(s1[0] - mns), p5 = __expf(s1[1] - mns);
        const float p6 = __expf(s1[2] - mns), p7 = __expf(s1[3] - mns);
        l += ((p0 + p1) + (p2 + p3)) + ((p4 + p5) + (p6 + p7));
        union { f16raw2 h2; uint u; } c0, c1, c2, c3;
        c0.h2 = __builtin_amdgcn_cvt_pkrtz(p0, p1);
        c1.h2 = __builtin_amdgcn_cvt_pkrtz(p2, p3);
        c2.h2 = __builtin_amdgcn_cvt_pkrtz(p4, p5);
        c3.h2 = __builtin_amdgcn_cvt_pkrtz(p6, p7);
        union { uint u[4]; f16x8 h; } P;
        P.u[0] = c0.u; P.u[1] = c1.u; P.u[2] = c2.u; P.u[3] = c3.u;
        asm volatile("s_waitcnt lgkmcnt(0)" ::: "memory");
        __builtin_amdgcn_sched_barrier(0);
        union { u32x2 d[2]; f16x8 h; } VA0, VA1;
        VA0.d[0] = t0; VA0.d[1] = t1;
        VA1.d[0] = t2; VA1.d[1] = t3;
        oc0 = __builtin_amdgcn_mfma_f32_16x16x32_f16(VA0.h, P.h, oc0, 0, 0, 0);
        oc1 = __builtin_amdgcn_mfma_f32_16x16x32_f16(VA1.h, P.h, oc1, 0, 0, 0);
    }

    // ---- finalize ----
    l += __shfl_xor(l, 16);
    l += __shfl_xor(l, 32);
    const float inv = 1.0f / l;
    union { f16raw2 h2; uint u; } w00, w01, w10, w11;
    w00.h2 = __builtin_amdgcn_cvt_pkrtz(oc0[0] * inv, oc0[1] * inv);
    w01.h2 = __builtin_amdgcn_cvt_pkrtz(oc0[2] * inv, oc0[3] * inv);
    w10.h2 = __builtin_amdgcn_cvt_pkrtz(oc1[0] * inv, oc1[1] * inv);
    w11.h2 = __builtin_amdgcn_cvt_pkrtz(oc1[2] * inv, oc1[3] * inv);
    ushort* cp = ctx + ((size_t)b * SEQ + (iq - MEMN)) * DIM
               + h * HEAD_DIM + fq4;
    *(uint2*)cp        = (uint2){w00.u, w01.u};
    *(uint2*)(cp + 16) = (uint2){w10.u, w11.u};
}

// ---------------------------------------------------------------------------
extern "C" void kernel_launch(void* const* d_in, const int* in_sizes, int n_in,
                              void* d_out, int out_size, void* d_ws, size_t ws_size,
                              hipStream_t stream) {
    const float* q    = (const float*)d_in[0];
    const float* k    = (const float*)d_in[1];
    const float* v    = (const float*)d_in[2];
    const float* memp = (const float*)d_in[3];
    const float* Wq   = (const float*)d_in[4];
    const float* bq   = (const float*)d_in[5];
    const float* Wk   = (const float*)d_in[6];
    const float* bk   = (const float*)d_in[7];
    const float* Wv   = (const float*)d_in[8];
    const float* bv   = (const float*)d_in[9];
    const float* Wo   = (const float*)d_in[10];
    const float* bo   = (const float*)d_in[11];
    float* out = (float*)d_out;

    const size_t NX = (size_t)MROWS * DIM;
    const size_t NW = (size_t)DIM * DIM;
    const size_t NC = (size_t)OROWS * DIM;

    ushort* p   = (ushort*)d_ws;
    ushort* Xq  = p;            p += NX;
    ushort* Xk  = p;            p += NX;
    ushort* Xv  = p;            p += NX;
    ushort* Qc  = p;            p += NX;
    ushort* Kc  = p;            p += NX;
    ushort* Vc  = p;            p += NX;
    ushort* Wtq = p;            p += NW;
    ushort* Wtk = p;            p += NW;
    ushort* Wtv = p;            p += NW;
    ushort* Wto = p;            p += NW;
    ushort* Cc  = p;            p += NC;               // ~31.7 MB total

    dim3 gp((MROWS * DIM / 16 + 255) / 256, 1, 7);     // 516 x 1 x 7
    prep_cvt<<<gp, 256, 0, stream>>>(q, k, v, memp, Wq, Wk, Wv, Wo,
                                     Xq, Xk, Xv, Wtq, Wtk, Wtv, Wto);

    dim3 g1((MROWS + 63) / 64, 4, 3);                  // 65 x 4 x 3 = 780 blocks
    gemm_qkv<<<g1, 256, 0, stream>>>(Xq, Xk, Xv, Wtq, Wtk, Wtv,
                                     bq, bk, bv, Qc, Kc, Vc);

    dim3 g2(SEQ / QT, NUM_HEADS, BATCH);
    attn_mfma<<<g2, 512, 0, stream>>>(Qc, Kc, Vc, Cc);

    dim3 g3(OROWS / 64, 4, 1);                         // 64 x 4 = 256 blocks
    gemm_out64<<<g3, 256, 0, stream>>>(Cc, Wto, bo, out);
}